// Round 4
// baseline (1140.094 us; speedup 1.0000x reference)
//
#include <hip/hip_runtime.h>
#include <math.h>

#define LSEQ   4096
#define DMODEL 512
#define NSTATE 8
#define NBATCH 16

typedef unsigned int   uint32;
typedef unsigned short ushort16_t;

__device__ __forceinline__ uint32 f32_to_bf16_rne(float f) {
    uint32 x = __float_as_uint(f);
    return (x + 0x7FFFu + ((x >> 16) & 1u)) >> 16;
}
__device__ __forceinline__ float bf16lo_to_f32(uint32 w) {   // low 16 bits
    return __uint_as_float(w << 16);
}
__device__ __forceinline__ float bf16hi_to_f32(uint32 w) {   // high 16 bits
    return __uint_as_float(w & 0xFFFF0000u);
}

// ---------------------------------------------------------------------------
// Kernel 1: S4D via prefix-scan of exp(dtA*m)*u[m], postfactor exp(dtA*(L-1-l)).
// One block per (b, c). 256 threads, each owns a contiguous chunk of 16.
// Fuses +u*D and exact GELU. OUTMODE: 0 = fp32 y_act, 1 = bf16 y_act.
// ---------------------------------------------------------------------------
template<int OUTMODE>
__global__ __launch_bounds__(256) void s4d_scan_kernel(
    const float* __restrict__ u,
    const float* __restrict__ log_dt,
    const float* __restrict__ log_A_real,
    const float* __restrict__ A_imag,
    const float* __restrict__ B_re, const float* __restrict__ B_im,
    const float* __restrict__ C_re, const float* __restrict__ C_im,
    const float* __restrict__ Dvec,
    void* __restrict__ y_act)
{
    const int c    = blockIdx.x;
    const int b    = blockIdx.y;
    const int t    = threadIdx.x;
    const int lane = t & 63;
    const int wave = t >> 6;

    // per-state constants: 0 dtA_re, 1 dtA_im, 2 Abar_re, 3 Abar_im,
    //                      4 AbarInv_re, 5 AbarInv_im, 6 w_re, 7 w_im
    __shared__ float sc[8][NSTATE];
    __shared__ float sD;
    __shared__ float swr[NSTATE][4], swi[NSTATE][4];

    if (t < NSTATE) {
        const int n = t;
        float dt  = expf(log_dt[c]);
        float Are = -expf(log_A_real[c*NSTATE + n]);
        float Aim = A_imag[c*NSTATE + n];
        float dre = Are * dt, dim = Aim * dt;
        float er  = expf(dre);
        float sn, cs; sincosf(dim, &sn, &cs);
        float Abr = er * cs, Abi = er * sn;          // A_bar = exp(dtA)
        float eri = expf(-dre);
        float Air = eri * cs, Aii = -eri * sn;       // exp(-dtA)
        // B_bar = (A_bar - 1)/A * Bc ;  w = Cc * B_bar
        float nr = Abr - 1.0f, ni = Abi;
        float den = Are*Are + Aim*Aim;
        float qr = (nr*Are + ni*Aim) / den;
        float qi = (ni*Are - nr*Aim) / den;
        float Br = B_re[c*NSTATE + n], Bi = B_im[c*NSTATE + n];
        float Bbr = qr*Br - qi*Bi, Bbi = qr*Bi + qi*Br;
        float Cr = C_re[c*NSTATE + n], Ci = C_im[c*NSTATE + n];
        float wr = Cr*Bbr - Ci*Bbi, wi = Cr*Bbi + Ci*Bbr;
        sc[0][n]=dre; sc[1][n]=dim; sc[2][n]=Abr; sc[3][n]=Abi;
        sc[4][n]=Air; sc[5][n]=Aii; sc[6][n]=wr;  sc[7][n]=wi;
    }
    if (t == 0) sD = Dvec[c];
    __syncthreads();

    const int    l0   = t * 16;
    const size_t base = ((size_t)b * DMODEL + c) * LSEQ;

    float uv[16];
    {
        const float4* up = reinterpret_cast<const float4*>(u + base + l0);
        #pragma unroll
        for (int i = 0; i < 4; i++) {
            float4 v = up[i];
            uv[4*i+0]=v.x; uv[4*i+1]=v.y; uv[4*i+2]=v.z; uv[4*i+3]=v.w;
        }
    }

    // ---- pass 1: per-thread totals of v_m = exp(dtA*m)*u[m] over the chunk
    float e1r[NSTATE], e1i[NSTATE], Tr[NSTATE], Ti[NSTATE];
    const float fl0 = (float)l0;
    #pragma unroll
    for (int n = 0; n < NSTATE; n++) {
        float dre = sc[0][n], dim = sc[1][n];
        float er = expf(dre * fl0);
        float sn, cs; sincosf(dim * fl0, &sn, &cs);
        float cr = er * cs, ci = er * sn;            // exp(dtA * l0)
        e1r[n] = cr; e1i[n] = ci;
        float Abr = sc[2][n], Abi = sc[3][n];
        float tr = 0.0f, ti = 0.0f;
        #pragma unroll
        for (int j = 0; j < 16; j++) {
            tr = fmaf(cr, uv[j], tr);
            ti = fmaf(ci, uv[j], ti);
            float t2 = cr*Abr - ci*Abi;
            ci = cr*Abi + ci*Abr;
            cr = t2;
        }
        Tr[n] = tr; Ti[n] = ti;
    }

    // ---- block exclusive scan over thread totals (8 independent states)
    float offr[NSTATE], offi[NSTATE];
    #pragma unroll
    for (int n = 0; n < NSTATE; n++) {
        float vr = Tr[n], vi = Ti[n];
        #pragma unroll
        for (int d = 1; d < 64; d <<= 1) {
            float xr = __shfl_up(vr, d);
            float xi = __shfl_up(vi, d);
            if (lane >= d) { vr += xr; vi += xi; }
        }
        if (lane == 63) { swr[n][wave] = vr; swi[n][wave] = vi; }
        offr[n] = vr - Tr[n]; offi[n] = vi - Ti[n];
    }
    __syncthreads();
    #pragma unroll
    for (int n = 0; n < NSTATE; n++) {
        #pragma unroll
        for (int w = 0; w < 4; w++) {
            if (w < wave) { offr[n] += swr[n][w]; offi[n] += swi[n][w]; }
        }
    }

    // ---- pass 2: y[l] = Re( (w * exp(dtA*(L-1-l))) * S[l] )
    float yv[16];
    #pragma unroll
    for (int j = 0; j < 16; j++) yv[j] = 0.0f;
    const float flp = (float)(LSEQ - 1 - l0);
    #pragma unroll
    for (int n = 0; n < NSTATE; n++) {
        float dre = sc[0][n], dim = sc[1][n];
        float er = expf(dre * flp);
        float sn, cs; sincosf(dim * flp, &sn, &cs);
        float p0r = er * cs, p0i = er * sn;          // exp(dtA*(L-1-l0))
        float wr = sc[6][n], wi = sc[7][n];
        float pr = wr*p0r - wi*p0i;                  // fold w into postfactor
        float pi = wr*p0i + wi*p0r;
        float Abr = sc[2][n], Abi = sc[3][n];
        float Air = sc[4][n], Aii = sc[5][n];
        float cr = e1r[n], ci = e1i[n];
        float rr = offr[n], ri = offi[n];
        #pragma unroll
        for (int j = 0; j < 16; j++) {
            rr = fmaf(cr, uv[j], rr);                // S[l] inclusive
            ri = fmaf(ci, uv[j], ri);
            yv[j] = fmaf(pr, rr, yv[j]);
            yv[j] = fmaf(-pi, ri, yv[j]);
            float t2 = cr*Abr - ci*Abi; ci = cr*Abi + ci*Abr; cr = t2;
            float p2 = pr*Air - pi*Aii; pi = pr*Aii + pi*Air; pr = p2;
        }
    }

    // ---- +u*D, exact GELU, store
    const float Dc = sD;
    #pragma unroll
    for (int j = 0; j < 16; j++) {
        float x = yv[j] + uv[j] * Dc;
        yv[j] = 0.5f * x * (1.0f + erff(x * 0.70710678118654752f));
    }
    if (OUTMODE == 0) {
        float4* yp = reinterpret_cast<float4*>((float*)y_act + base + l0);
        #pragma unroll
        for (int i = 0; i < 4; i++) {
            float4 v; v.x=yv[4*i+0]; v.y=yv[4*i+1]; v.z=yv[4*i+2]; v.w=yv[4*i+3];
            yp[i] = v;
        }
    } else {
        uint32 us[16];
        #pragma unroll
        for (int j = 0; j < 16; j++) us[j] = f32_to_bf16_rne(yv[j]);
        uint4 p0, p1;
        p0.x = us[0]  | (us[1]  << 16); p0.y = us[2]  | (us[3]  << 16);
        p0.z = us[4]  | (us[5]  << 16); p0.w = us[6]  | (us[7]  << 16);
        p1.x = us[8]  | (us[9]  << 16); p1.y = us[10] | (us[11] << 16);
        p1.z = us[12] | (us[13] << 16); p1.w = us[14] | (us[15] << 16);
        uint4* yp = reinterpret_cast<uint4*>((ushort16_t*)y_act + base + l0);
        yp[0] = p0; yp[1] = p1;
    }
}

// ---------------------------------------------------------------------------
// Kernel 2: z = W_out @ y_act (+bias), GLU, weight by W_dec, reduce over
// (o, l) into per-batch accumulators. fp32 vector GEMM, LDS tiled.
// grid: x = 8 n-tiles (64 a-rows + paired 64 g-rows), y = 512 position tiles.
// INMODE: 0 = fp32 y_act, 1 = bf16 y_act (converted to fp32 during staging).
// ---------------------------------------------------------------------------
#define MT 128
#define KB 32

template<int INMODE>
__global__ __launch_bounds__(256) void gemm_glu_reduce_kernel(
    const void* __restrict__ y_act,    // [B, C, L]
    const float* __restrict__ W,       // [1024, 512]
    const float* __restrict__ b_out,   // [1024]
    const float* __restrict__ W_dec,   // [512]
    float* __restrict__ acc)           // [16]
{
    const int nt = blockIdx.x;          // 0..7
    const int mt = blockIdx.y;          // 0..511
    const int b  = mt >> 5;             // 32 tiles per batch
    const int l0 = (mt & 31) * MT;
    const int n0 = nt * 64;
    const int t  = threadIdx.x;
    const int tn = t >> 4;              // 0..15  (output-row group)
    const int tm = t & 15;              // 0..15  (position group)

    __shared__ float Ws[128][36];       // rows 0..63: a (o=n0+r); 64..127: g (o=512+n0+r-64)
    __shared__ float Ys[KB][132];

    float accv[8][8];
    #pragma unroll
    for (int i = 0; i < 8; i++)
        #pragma unroll
        for (int j = 0; j < 8; j++) accv[i][j] = 0.0f;

    for (int k0 = 0; k0 < DMODEL; k0 += KB) {
        #pragma unroll
        for (int i = 0; i < 4; i++) {              // stage W tile (128x32)
            int f = t + i*256;
            int r = f >> 3, c4 = f & 7;
            int o = (r < 64) ? (n0 + r) : (448 + n0 + r);
            float4 v = *reinterpret_cast<const float4*>(W + (size_t)o*DMODEL + k0 + c4*4);
            *reinterpret_cast<float4*>(&Ws[r][c4*4]) = v;
        }
        if (INMODE == 0) {
            #pragma unroll
            for (int i = 0; i < 4; i++) {          // stage Y tile (32x128) fp32
                int f = t + i*256;
                int r = f >> 5, c4 = f & 31;
                float4 v = *reinterpret_cast<const float4*>(
                    (const float*)y_act + ((size_t)b*DMODEL + k0 + r)*LSEQ + l0 + c4*4);
                *reinterpret_cast<float4*>(&Ys[r][c4*4]) = v;
            }
        } else {
            // stage Y tile (32x128) bf16 -> fp32; 16 elements per thread
            int r  = t >> 3;            // 0..31
            int c0 = (t & 7) * 16;      // 0,16,...,112
            const uint4* src = reinterpret_cast<const uint4*>(
                (const ushort16_t*)y_act + ((size_t)b*DMODEL + k0 + r)*LSEQ + l0 + c0);
            uint4 h0 = src[0], h1 = src[1];
            float4 q;
            q.x = bf16lo_to_f32(h0.x); q.y = bf16hi_to_f32(h0.x);
            q.z = bf16lo_to_f32(h0.y); q.w = bf16hi_to_f32(h0.y);
            *reinterpret_cast<float4*>(&Ys[r][c0 + 0]) = q;
            q.x = bf16lo_to_f32(h0.z); q.y = bf16hi_to_f32(h0.z);
            q.z = bf16lo_to_f32(h0.w); q.w = bf16hi_to_f32(h0.w);
            *reinterpret_cast<float4*>(&Ys[r][c0 + 4]) = q;
            q.x = bf16lo_to_f32(h1.x); q.y = bf16hi_to_f32(h1.x);
            q.z = bf16lo_to_f32(h1.y); q.w = bf16hi_to_f32(h1.y);
            *reinterpret_cast<float4*>(&Ys[r][c0 + 8]) = q;
            q.x = bf16lo_to_f32(h1.z); q.y = bf16hi_to_f32(h1.z);
            q.z = bf16lo_to_f32(h1.w); q.w = bf16hi_to_f32(h1.w);
            *reinterpret_cast<float4*>(&Ys[r][c0 + 12]) = q;
        }
        __syncthreads();

        #pragma unroll
        for (int kq = 0; kq < KB; kq += 4) {
            float4 A[8];
            #pragma unroll
            for (int i = 0; i < 4; i++) {
                A[i]   = *reinterpret_cast<const float4*>(&Ws[tn*4 + i][kq]);
                A[4+i] = *reinterpret_cast<const float4*>(&Ws[64 + tn*4 + i][kq]);
            }
            #pragma unroll
            for (int q = 0; q < 4; q++) {
                float4 y0 = *reinterpret_cast<const float4*>(&Ys[kq+q][tm*8]);
                float4 y1 = *reinterpret_cast<const float4*>(&Ys[kq+q][tm*8+4]);
                float ym[8] = {y0.x,y0.y,y0.z,y0.w,y1.x,y1.y,y1.z,y1.w};
                #pragma unroll
                for (int i = 0; i < 8; i++) {
                    float a = (q==0) ? A[i].x : (q==1) ? A[i].y : (q==2) ? A[i].z : A[i].w;
                    #pragma unroll
                    for (int j = 0; j < 8; j++)
                        accv[i][j] = fmaf(a, ym[j], accv[i][j]);
                }
            }
        }
        __syncthreads();
    }

    // epilogue: bias, GLU, W_dec weighting, reduce
    float part = 0.0f;
    #pragma unroll
    for (int i = 0; i < 4; i++) {
        int o = n0 + tn*4 + i;
        float ba = b_out[o], bg = b_out[512 + o], wd = W_dec[o];
        #pragma unroll
        for (int j = 0; j < 8; j++) {
            float a = accv[i][j]   + ba;
            float g = accv[4+i][j] + bg;
            float s = 1.0f / (1.0f + expf(-g));
            part = fmaf(wd * a, s, part);
        }
    }
    #pragma unroll
    for (int d = 32; d > 0; d >>= 1) part += __shfl_down(part, d);
    __shared__ float red[4];
    if ((t & 63) == 0) red[t >> 6] = part;
    __syncthreads();
    if (t == 0) atomicAdd(&acc[b], red[0] + red[1] + red[2] + red[3]);
}

__global__ void finalize_kernel(const float* __restrict__ acc,
                                const float* __restrict__ b_dec,
                                float* __restrict__ out)
{
    int i = threadIdx.x;
    if (i < NBATCH) out[i] = acc[i] * (1.0f / (float)LSEQ) + b_dec[0];
}

// ---------------------------------------------------------------------------
extern "C" void kernel_launch(void* const* d_in, const int* in_sizes, int n_in,
                              void* d_out, int out_size, void* d_ws, size_t ws_size,
                              hipStream_t stream)
{
    const float* u          = (const float*)d_in[0];
    const float* log_dt     = (const float*)d_in[1];
    const float* log_A_real = (const float*)d_in[2];
    const float* A_imag     = (const float*)d_in[3];
    const float* B_re       = (const float*)d_in[4];
    const float* B_im       = (const float*)d_in[5];
    const float* C_re       = (const float*)d_in[6];
    const float* C_im       = (const float*)d_in[7];
    const float* Dvec       = (const float*)d_in[8];
    const float* W_out      = (const float*)d_in[9];
    const float* b_out      = (const float*)d_in[10];
    const float* W_dec      = (const float*)d_in[11];
    const float* b_dec      = (const float*)d_in[12];

    float* acc   = (float*)d_ws;          // 16 accumulators (64-float slot)
    void*  y_act = (void*)((float*)d_ws + 64);

    const size_t need_f32 = 64*sizeof(float) + (size_t)NBATCH*DMODEL*LSEQ*sizeof(float);
    const bool   use_f32  = (ws_size >= need_f32);

    hipMemsetAsync(acc, 0, 64 * sizeof(float), stream);

    if (use_f32) {
        s4d_scan_kernel<0><<<dim3(DMODEL, NBATCH), 256, 0, stream>>>(
            u, log_dt, log_A_real, A_imag, B_re, B_im, C_re, C_im, Dvec, y_act);
        gemm_glu_reduce_kernel<0><<<dim3(8, 512), 256, 0, stream>>>(
            y_act, W_out, b_out, W_dec, acc);
    } else {
        s4d_scan_kernel<1><<<dim3(DMODEL, NBATCH), 256, 0, stream>>>(
            u, log_dt, log_A_real, A_imag, B_re, B_im, C_re, C_im, Dvec, y_act);
        gemm_glu_reduce_kernel<1><<<dim3(8, 512), 256, 0, stream>>>(
            y_act, W_out, b_out, W_dec, acc);
    }

    finalize_kernel<<<1, 64, 0, stream>>>(acc, b_dec, (float*)d_out);
}

// Round 5
// 526.087 us; speedup vs baseline: 2.1671x; 2.1671x over previous
//
#include <hip/hip_runtime.h>
#include <math.h>

#define LSEQ   4096
#define DMODEL 512
#define NSTATE 8
#define NBATCH 16

typedef unsigned int   uint32;
typedef unsigned short u16;

typedef __attribute__((ext_vector_type(8))) short short8v;  // 8 bf16 = 4 VGPR
typedef __attribute__((ext_vector_type(4))) float f32x4;    // MFMA acc

__device__ __forceinline__ uint32 f32_to_bf16_rne(float f) {
    uint32 x = __float_as_uint(f);
    return (x + 0x7FFFu + ((x >> 16) & 1u)) >> 16;
}

// ---------------------------------------------------------------------------
// Kernel 1: S4D via prefix-scan of exp(dtA*m)*u[m], postfactor exp(dtA*(L-1-l)).
// One block per (b, c). Fuses +u*D and exact GELU. Writes y_act bf16.
// (unchanged from round 4's bf16 path, which passed with absmax 0.0)
// ---------------------------------------------------------------------------
__global__ __launch_bounds__(256) void s4d_scan_kernel(
    const float* __restrict__ u,
    const float* __restrict__ log_dt,
    const float* __restrict__ log_A_real,
    const float* __restrict__ A_imag,
    const float* __restrict__ B_re, const float* __restrict__ B_im,
    const float* __restrict__ C_re, const float* __restrict__ C_im,
    const float* __restrict__ Dvec,
    u16* __restrict__ y_act)
{
    const int c    = blockIdx.x;
    const int b    = blockIdx.y;
    const int t    = threadIdx.x;
    const int lane = t & 63;
    const int wave = t >> 6;

    __shared__ float sc[8][NSTATE];
    __shared__ float sD;
    __shared__ float swr[NSTATE][4], swi[NSTATE][4];

    if (t < NSTATE) {
        const int n = t;
        float dt  = expf(log_dt[c]);
        float Are = -expf(log_A_real[c*NSTATE + n]);
        float Aim = A_imag[c*NSTATE + n];
        float dre = Are * dt, dim = Aim * dt;
        float er  = expf(dre);
        float sn, cs; sincosf(dim, &sn, &cs);
        float Abr = er * cs, Abi = er * sn;
        float eri = expf(-dre);
        float Air = eri * cs, Aii = -eri * sn;
        float nr = Abr - 1.0f, ni = Abi;
        float den = Are*Are + Aim*Aim;
        float qr = (nr*Are + ni*Aim) / den;
        float qi = (ni*Are - nr*Aim) / den;
        float Br = B_re[c*NSTATE + n], Bi = B_im[c*NSTATE + n];
        float Bbr = qr*Br - qi*Bi, Bbi = qr*Bi + qi*Br;
        float Cr = C_re[c*NSTATE + n], Ci = C_im[c*NSTATE + n];
        float wr = Cr*Bbr - Ci*Bbi, wi = Cr*Bbi + Ci*Bbr;
        sc[0][n]=dre; sc[1][n]=dim; sc[2][n]=Abr; sc[3][n]=Abi;
        sc[4][n]=Air; sc[5][n]=Aii; sc[6][n]=wr;  sc[7][n]=wi;
    }
    if (t == 0) sD = Dvec[c];
    __syncthreads();

    const int    l0   = t * 16;
    const size_t base = ((size_t)b * DMODEL + c) * LSEQ;

    float uv[16];
    {
        const float4* up = reinterpret_cast<const float4*>(u + base + l0);
        #pragma unroll
        for (int i = 0; i < 4; i++) {
            float4 v = up[i];
            uv[4*i+0]=v.x; uv[4*i+1]=v.y; uv[4*i+2]=v.z; uv[4*i+3]=v.w;
        }
    }

    float e1r[NSTATE], e1i[NSTATE], Tr[NSTATE], Ti[NSTATE];
    const float fl0 = (float)l0;
    #pragma unroll
    for (int n = 0; n < NSTATE; n++) {
        float dre = sc[0][n], dim = sc[1][n];
        float er = expf(dre * fl0);
        float sn, cs; sincosf(dim * fl0, &sn, &cs);
        float cr = er * cs, ci = er * sn;
        e1r[n] = cr; e1i[n] = ci;
        float Abr = sc[2][n], Abi = sc[3][n];
        float tr = 0.0f, ti = 0.0f;
        #pragma unroll
        for (int j = 0; j < 16; j++) {
            tr = fmaf(cr, uv[j], tr);
            ti = fmaf(ci, uv[j], ti);
            float t2 = cr*Abr - ci*Abi;
            ci = cr*Abi + ci*Abr;
            cr = t2;
        }
        Tr[n] = tr; Ti[n] = ti;
    }

    float offr[NSTATE], offi[NSTATE];
    #pragma unroll
    for (int n = 0; n < NSTATE; n++) {
        float vr = Tr[n], vi = Ti[n];
        #pragma unroll
        for (int d = 1; d < 64; d <<= 1) {
            float xr = __shfl_up(vr, d);
            float xi = __shfl_up(vi, d);
            if (lane >= d) { vr += xr; vi += xi; }
        }
        if (lane == 63) { swr[n][wave] = vr; swi[n][wave] = vi; }
        offr[n] = vr - Tr[n]; offi[n] = vi - Ti[n];
    }
    __syncthreads();
    #pragma unroll
    for (int n = 0; n < NSTATE; n++) {
        #pragma unroll
        for (int w = 0; w < 4; w++) {
            if (w < wave) { offr[n] += swr[n][w]; offi[n] += swi[n][w]; }
        }
    }

    float yv[16];
    #pragma unroll
    for (int j = 0; j < 16; j++) yv[j] = 0.0f;
    const float flp = (float)(LSEQ - 1 - l0);
    #pragma unroll
    for (int n = 0; n < NSTATE; n++) {
        float dre = sc[0][n], dim = sc[1][n];
        float er = expf(dre * flp);
        float sn, cs; sincosf(dim * flp, &sn, &cs);
        float p0r = er * cs, p0i = er * sn;
        float wr = sc[6][n], wi = sc[7][n];
        float pr = wr*p0r - wi*p0i;
        float pi = wr*p0i + wi*p0r;
        float Abr = sc[2][n], Abi = sc[3][n];
        float Air = sc[4][n], Aii = sc[5][n];
        float cr = e1r[n], ci = e1i[n];
        float rr = offr[n], ri = offi[n];
        #pragma unroll
        for (int j = 0; j < 16; j++) {
            rr = fmaf(cr, uv[j], rr);
            ri = fmaf(ci, uv[j], ri);
            yv[j] = fmaf(pr, rr, yv[j]);
            yv[j] = fmaf(-pi, ri, yv[j]);
            float t2 = cr*Abr - ci*Abi; ci = cr*Abi + ci*Abr; cr = t2;
            float p2 = pr*Air - pi*Aii; pi = pr*Aii + pi*Air; pr = p2;
        }
    }

    const float Dc = sD;
    #pragma unroll
    for (int j = 0; j < 16; j++) {
        float x = yv[j] + uv[j] * Dc;
        yv[j] = 0.5f * x * (1.0f + erff(x * 0.70710678118654752f));
    }
    {
        uint32 us[16];
        #pragma unroll
        for (int j = 0; j < 16; j++) us[j] = f32_to_bf16_rne(yv[j]);
        uint4 p0, p1;
        p0.x = us[0]  | (us[1]  << 16); p0.y = us[2]  | (us[3]  << 16);
        p0.z = us[4]  | (us[5]  << 16); p0.w = us[6]  | (us[7]  << 16);
        p1.x = us[8]  | (us[9]  << 16); p1.y = us[10] | (us[11] << 16);
        p1.z = us[12] | (us[13] << 16); p1.w = us[14] | (us[15] << 16);
        uint4* yp = reinterpret_cast<uint4*>(y_act + base + l0);
        yp[0] = p0; yp[1] = p1;
    }
}

// ---------------------------------------------------------------------------
// Optional: W fp32 -> (W_hi, W_lo) bf16 split, cached in ws (if it fits).
// hi = truncation (top 16 bits), lo = rne(residual): ~16-bit mantissa total.
// ---------------------------------------------------------------------------
__global__ __launch_bounds__(256) void wconv_kernel(const float* __restrict__ W,
                                                    u16* __restrict__ Whi,
                                                    u16* __restrict__ Wlo)
{
    int i = blockIdx.x * 256 + threadIdx.x;      // 4 floats per thread, 512 blocks
    float4 v = reinterpret_cast<const float4*>(W)[i];
    float f[4] = {v.x, v.y, v.z, v.w};
    uint32 h[4], l[4];
    #pragma unroll
    for (int j = 0; j < 4; j++) {
        h[j] = __float_as_uint(f[j]) >> 16;
        float fhi = __uint_as_float(h[j] << 16);
        l[j] = f32_to_bf16_rne(f[j] - fhi);
    }
    uint2 hp, lp;
    hp.x = h[0] | (h[1] << 16); hp.y = h[2] | (h[3] << 16);
    lp.x = l[0] | (l[1] << 16); lp.y = l[2] | (l[3] << 16);
    reinterpret_cast<uint2*>(Whi)[i] = hp;
    reinterpret_cast<uint2*>(Wlo)[i] = lp;
}

// ---------------------------------------------------------------------------
// Kernel 2: MFMA bf16 GEMM + GLU + weighted reduce.
// D[m=l][n=o] = y^T @ W^T. Block: M=256 l, N=64 o-pairs (a & g rows), K-step 32.
// 4 waves, each owns M=64. y transposed into LDS during staging (b32-packed
// writes); W staged as hi/lo bf16 (split fp32). 80B LDS row pitch -> frag
// reads conflict-free. Single-barrier double buffer.
// ---------------------------------------------------------------------------
#define GBM 256
#define GBN 64
#define GBK 32

template<int WCACHED>
__global__ __launch_bounds__(256, 2) void gemm_mfma_kernel(
    const u16* __restrict__ y,        // [B][512][4096] bf16
    const float* __restrict__ W,      // [1024][512] fp32
    const u16* __restrict__ Whi,      // [1024][512] bf16 (WCACHED only)
    const u16* __restrict__ Wlo,
    const float* __restrict__ b_out,
    const float* __restrict__ W_dec,
    float* __restrict__ acc)
{
    const int mt = blockIdx.x;   // 0..15 (l tiles)
    const int nt = blockIdx.y;   // 0..7  (o-pair tiles)
    const int b  = blockIdx.z;   // 0..15
    const int t  = threadIdx.x;
    const int wv = t >> 6, ln = t & 63;
    const int l0 = mt * GBM, n0 = nt * GBN;

    // 81920 B total: Yt [2][256][40] bf16, Wt [2][2][128][40] bf16
    __shared__ u16 lds[40960];
    u16* Yt = lds;             // cur*10240 + l*40 + k
    u16* Wt = lds + 20480;     // cur*10240 + hl*5120 + r*40 + k  (r<64:a, r>=64:g)

    // staging roles
    const int sy_k2 = (t & 15) * 2;   // k pair within K-tile
    const int sy_lc = t >> 4;         // l chunk (16 l)
    const int sw_r  = t & 127;        // W tile row
    const int sw_kh = t >> 7;         // W k half (16 k)
    const int sw_o  = (sw_r < 64) ? (n0 + sw_r) : (448 + n0 + sw_r);

    const u16* ybase = y + (size_t)b * DMODEL * LSEQ;

    f32x4 accA[4][4], accG[4][4];
    #pragma unroll
    for (int i = 0; i < 4; i++)
        #pragma unroll
        for (int j = 0; j < 4; j++)
            #pragma unroll
            for (int r = 0; r < 4; r++) { accA[i][j][r] = 0.0f; accG[i][j][r] = 0.0f; }

    uint4 ya0, ya1, yc0, yc1;          // y stage regs (2 k-rows x 16 l)
    uint4 wh0, wh1, wl0, wl1;          // W stage regs (cached path)
    float4 wf0, wf1, wf2, wf3;         // W stage regs (fp32 path)

#define STAGE_LOAD(K0) do {                                                               \
    const uint4* _p0 = reinterpret_cast<const uint4*>(                                    \
        ybase + (size_t)((K0) + sy_k2) * LSEQ + l0 + sy_lc*16);                           \
    const uint4* _p1 = reinterpret_cast<const uint4*>(                                    \
        ybase + (size_t)((K0) + sy_k2 + 1) * LSEQ + l0 + sy_lc*16);                       \
    ya0 = _p0[0]; ya1 = _p0[1]; yc0 = _p1[0]; yc1 = _p1[1];                               \
    if (WCACHED) {                                                                        \
        const uint4* _h = reinterpret_cast<const uint4*>(Whi + (size_t)sw_o*DMODEL + (K0) + sw_kh*16); \
        const uint4* _l = reinterpret_cast<const uint4*>(Wlo + (size_t)sw_o*DMODEL + (K0) + sw_kh*16); \
        wh0 = _h[0]; wh1 = _h[1]; wl0 = _l[0]; wl1 = _l[1];                               \
    } else {                                                                              \
        const float4* _f = reinterpret_cast<const float4*>(W + (size_t)sw_o*DMODEL + (K0) + sw_kh*16); \
        wf0 = _f[0]; wf1 = _f[1]; wf2 = _f[2]; wf3 = _f[3];                               \
    }                                                                                     \
} while (0)

#define STAGE_WRITE(BUF) do {                                                             \
    u16* _yt = Yt + (BUF)*10240;                                                          \
    uint32 _aw[8] = {ya0.x, ya0.y, ya0.z, ya0.w, ya1.x, ya1.y, ya1.z, ya1.w};             \
    uint32 _bw[8] = {yc0.x, yc0.y, yc0.z, yc0.w, yc1.x, yc1.y, yc1.z, yc1.w};             \
    _Pragma("unroll")                                                                     \
    for (int _j = 0; _j < 8; _j++) {                                                      \
        uint32 _lo = (_aw[_j] & 0xFFFFu) | (_bw[_j] << 16);                               \
        uint32 _hi = (_aw[_j] >> 16) | (_bw[_j] & 0xFFFF0000u);                           \
        int _le = sy_lc*16 + 2*_j;                                                        \
        *reinterpret_cast<uint32*>(_yt + _le*40 + sy_k2)     = _lo;                       \
        *reinterpret_cast<uint32*>(_yt + (_le+1)*40 + sy_k2) = _hi;                       \
    }                                                                                     \
    u16* _wt = Wt + (BUF)*10240 + sw_r*40 + sw_kh*16;                                     \
    if (WCACHED) {                                                                        \
        *reinterpret_cast<uint4*>(_wt)        = wh0;                                      \
        *reinterpret_cast<uint4*>(_wt + 8)    = wh1;                                      \
        *reinterpret_cast<uint4*>(_wt + 5120)     = wl0;                                  \
        *reinterpret_cast<uint4*>(_wt + 5120 + 8) = wl1;                                  \
    } else {                                                                              \
        float _ff[16] = {wf0.x,wf0.y,wf0.z,wf0.w, wf1.x,wf1.y,wf1.z,wf1.w,                \
                         wf2.x,wf2.y,wf2.z,wf2.w, wf3.x,wf3.y,wf3.z,wf3.w};               \
        uint32 _hh[16], _ll[16];                                                          \
        _Pragma("unroll")                                                                 \
        for (int _j = 0; _j < 16; _j++) {                                                 \
            _hh[_j] = __float_as_uint(_ff[_j]) >> 16;                                     \
            float _fh = __uint_as_float(_hh[_j] << 16);                                   \
            _ll[_j] = f32_to_bf16_rne(_ff[_j] - _fh);                                     \
        }                                                                                 \
        uint4 _ph0, _ph1, _pl0, _pl1;                                                     \
        _ph0.x=_hh[0]|(_hh[1]<<16);  _ph0.y=_hh[2]|(_hh[3]<<16);                          \
        _ph0.z=_hh[4]|(_hh[5]<<16);  _ph0.w=_hh[6]|(_hh[7]<<16);                          \
        _ph1.x=_hh[8]|(_hh[9]<<16);  _ph1.y=_hh[10]|(_hh[11]<<16);                        \
        _ph1.z=_hh[12]|(_hh[13]<<16);_ph1.w=_hh[14]|(_hh[15]<<16);                        \
        _pl0.x=_ll[0]|(_ll[1]<<16);  _pl0.y=_ll[2]|(_ll[3]<<16);                          \
        _pl0.z=_ll[4]|(_ll[5]<<16);  _pl0.w=_ll[6]|(_ll[7]<<16);                          \
        _pl1.x=_ll[8]|(_ll[9]<<16);  _pl1.y=_ll[10]|(_ll[11]<<16);                        \
        _pl1.z=_ll[12]|(_ll[13]<<16);_pl1.w=_ll[14]|(_ll[15]<<16);                        \
        *reinterpret_cast<uint4*>(_wt)            = _ph0;                                 \
        *reinterpret_cast<uint4*>(_wt + 8)        = _ph1;                                 \
        *reinterpret_cast<uint4*>(_wt + 5120)     = _pl0;                                 \
        *reinterpret_cast<uint4*>(_wt + 5120 + 8) = _pl1;                                 \
    }                                                                                     \
} while (0)

    const int fr = ln & 15;      // frag row/col within 16
    const int fq = ln >> 4;      // frag k-quadrant

    STAGE_LOAD(0);
    STAGE_WRITE(0);
    __syncthreads();

    for (int kt = 0; kt < DMODEL / GBK; kt++) {
        const int cur = kt & 1;
        if (kt < DMODEL / GBK - 1) STAGE_LOAD((kt + 1) * GBK);

        short8v Af[4];
        #pragma unroll
        for (int mf = 0; mf < 4; mf++)
            Af[mf] = *reinterpret_cast<const short8v*>(
                Yt + cur*10240 + (wv*64 + mf*16 + fr)*40 + fq*8);

        #pragma unroll
        for (int nf = 0; nf < 4; nf++) {
            const u16* wb = Wt + cur*10240 + (nf*16 + fr)*40 + fq*8;
            short8v Bah = *reinterpret_cast<const short8v*>(wb);
            short8v Bal = *reinterpret_cast<const short8v*>(wb + 5120);
            short8v Bgh = *reinterpret_cast<const short8v*>(wb + 64*40);
            short8v Bgl = *reinterpret_cast<const short8v*>(wb + 5120 + 64*40);
            #pragma unroll
            for (int mf = 0; mf < 4; mf++) {
                accA[mf][nf] = __builtin_amdgcn_mfma_f32_16x16x32_bf16(Af[mf], Bah, accA[mf][nf], 0, 0, 0);
                accA[mf][nf] = __builtin_amdgcn_mfma_f32_16x16x32_bf16(Af[mf], Bal, accA[mf][nf], 0, 0, 0);
                accG[mf][nf] = __builtin_amdgcn_mfma_f32_16x16x32_bf16(Af[mf], Bgh, accG[mf][nf], 0, 0, 0);
                accG[mf][nf] = __builtin_amdgcn_mfma_f32_16x16x32_bf16(Af[mf], Bgl, accG[mf][nf], 0, 0, 0);
            }
        }

        if (kt < DMODEL / GBK - 1) STAGE_WRITE(cur ^ 1);
        __syncthreads();
    }

    // epilogue: bias, GLU, W_dec weight, reduce.  D mapping: col(o)=fr, row(l)=fq*4+r
    float part = 0.0f;
    #pragma unroll
    for (int nf = 0; nf < 4; nf++) {
        int o = n0 + nf*16 + fr;
        float ba = b_out[o], bg = b_out[512 + o], wd = W_dec[o];
        #pragma unroll
        for (int mf = 0; mf < 4; mf++)
            #pragma unroll
            for (int r = 0; r < 4; r++) {
                float a = accA[mf][nf][r] + ba;
                float g = accG[mf][nf][r] + bg;
                part = fmaf(wd * a, 1.0f / (1.0f + expf(-g)), part);
            }
    }
    #pragma unroll
    for (int d = 32; d > 0; d >>= 1) part += __shfl_down(part, d);
    float* red = reinterpret_cast<float*>(lds);   // LDS free after final barrier
    if (ln == 0) red[wv] = part;
    __syncthreads();
    if (t == 0) atomicAdd(&acc[b], red[0] + red[1] + red[2] + red[3]);

#undef STAGE_LOAD
#undef STAGE_WRITE
}

__global__ void finalize_kernel(const float* __restrict__ acc,
                                const float* __restrict__ b_dec,
                                float* __restrict__ out)
{
    int i = threadIdx.x;
    if (i < NBATCH) out[i] = acc[i] * (1.0f / (float)LSEQ) + b_dec[0];
}

// ---------------------------------------------------------------------------
extern "C" void kernel_launch(void* const* d_in, const int* in_sizes, int n_in,
                              void* d_out, int out_size, void* d_ws, size_t ws_size,
                              hipStream_t stream)
{
    const float* u          = (const float*)d_in[0];
    const float* log_dt     = (const float*)d_in[1];
    const float* log_A_real = (const float*)d_in[2];
    const float* A_imag     = (const float*)d_in[3];
    const float* B_re       = (const float*)d_in[4];
    const float* B_im       = (const float*)d_in[5];
    const float* C_re       = (const float*)d_in[6];
    const float* C_im       = (const float*)d_in[7];
    const float* Dvec       = (const float*)d_in[8];
    const float* W_out      = (const float*)d_in[9];
    const float* b_out      = (const float*)d_in[10];
    const float* W_dec      = (const float*)d_in[11];
    const float* b_dec      = (const float*)d_in[12];

    const size_t ybytes = (size_t)NBATCH * DMODEL * LSEQ * sizeof(u16);  // 67,108,864
    float* acc   = (float*)d_ws;                                  // 256 B
    u16*   y_act = (u16*)((char*)d_ws + 256);
    u16*   Whi   = (u16*)((char*)d_ws + 256 + ybytes);
    u16*   Wlo   = Whi + 1024 * DMODEL;
    const size_t need_cache = 256 + ybytes + (size_t)2 * 1024 * DMODEL * sizeof(u16);
    const bool wcached = (ws_size >= need_cache);   // deterministic -> graph-safe

    hipMemsetAsync(acc, 0, 64 * sizeof(float), stream);

    s4d_scan_kernel<<<dim3(DMODEL, NBATCH), 256, 0, stream>>>(
        u, log_dt, log_A_real, A_imag, B_re, B_im, C_re, C_im, Dvec, y_act);

    if (wcached) {
        wconv_kernel<<<512, 256, 0, stream>>>(W_out, Whi, Wlo);
        gemm_mfma_kernel<1><<<dim3(16, 8, 16), 256, 0, stream>>>(
            y_act, W_out, Whi, Wlo, b_out, W_dec, acc);
    } else {
        gemm_mfma_kernel<0><<<dim3(16, 8, 16), 256, 0, stream>>>(
            y_act, W_out, Whi, Wlo, b_out, W_dec, acc);
    }

    finalize_kernel<<<1, 64, 0, stream>>>(acc, b_dec, (float*)d_out);
}

// Round 6
// 504.730 us; speedup vs baseline: 2.2588x; 1.0423x over previous
//
#include <hip/hip_runtime.h>
#include <math.h>

#define LSEQ   4096
#define DMODEL 512
#define NSTATE 8
#define NBATCH 16

typedef unsigned int   uint32;
typedef unsigned short u16;

typedef __attribute__((ext_vector_type(8))) short short8v;  // 8 bf16 = 4 VGPR
typedef __attribute__((ext_vector_type(4))) float f32x4;    // MFMA acc

__device__ __forceinline__ uint32 f32_to_bf16_rne(float f) {
    uint32 x = __float_as_uint(f);
    return (x + 0x7FFFu + ((x >> 16) & 1u)) >> 16;
}

// ---------------------------------------------------------------------------
// Kernel 1: S4D scan, restructured for minimum VALU ops/element.
//  pass 1: local T = sum_j Abar^j u_j via DESCENDING Horner (4 ops/st/el),
//          then one complex mul by e0=exp(dtA*l0) -> global frame.
//  butterfly scan over thread totals (unchanged).
//  pass 2: V_j = AbarInv*V_{j-1} + E0*u_j  (V_{-1}=Abar*S_prev, E0=e0 const),
//          y_j += Re(P0*V_j), P0 = w*exp(dtA*(L-1-l0)) const.  8 ops/st/el.
// Fuses +u*D and exact GELU. Writes y_act bf16.
// ---------------------------------------------------------------------------
__global__ __launch_bounds__(256) void s4d_scan_kernel(
    const float* __restrict__ u,
    const float* __restrict__ log_dt,
    const float* __restrict__ log_A_real,
    const float* __restrict__ A_imag,
    const float* __restrict__ B_re, const float* __restrict__ B_im,
    const float* __restrict__ C_re, const float* __restrict__ C_im,
    const float* __restrict__ Dvec,
    u16* __restrict__ y_act)
{
    const int c    = blockIdx.x;
    const int b    = blockIdx.y;
    const int t    = threadIdx.x;
    const int lane = t & 63;
    const int wave = t >> 6;

    // per-state constants: 0 dtA_re, 1 dtA_im, 2 Abar_re, 3 Abar_im,
    //                      4 AbarInv_re, 5 AbarInv_im, 6 w_re, 7 w_im
    __shared__ float sc[8][NSTATE];
    __shared__ float sD;
    __shared__ float swr[NSTATE][4], swi[NSTATE][4];

    if (t < NSTATE) {
        const int n = t;
        float dt  = expf(log_dt[c]);
        float Are = -expf(log_A_real[c*NSTATE + n]);
        float Aim = A_imag[c*NSTATE + n];
        float dre = Are * dt, dim = Aim * dt;
        float er  = expf(dre);
        float sn, cs; sincosf(dim, &sn, &cs);
        float Abr = er * cs, Abi = er * sn;
        float eri = expf(-dre);
        float Air = eri * cs, Aii = -eri * sn;
        float nr = Abr - 1.0f, ni = Abi;
        float den = Are*Are + Aim*Aim;
        float qr = (nr*Are + ni*Aim) / den;
        float qi = (ni*Are - nr*Aim) / den;
        float Br = B_re[c*NSTATE + n], Bi = B_im[c*NSTATE + n];
        float Bbr = qr*Br - qi*Bi, Bbi = qr*Bi + qi*Br;
        float Cr = C_re[c*NSTATE + n], Ci = C_im[c*NSTATE + n];
        float wr = Cr*Bbr - Ci*Bbi, wi = Cr*Bbi + Ci*Bbr;
        sc[0][n]=dre; sc[1][n]=dim; sc[2][n]=Abr; sc[3][n]=Abi;
        sc[4][n]=Air; sc[5][n]=Aii; sc[6][n]=wr;  sc[7][n]=wi;
    }
    if (t == 0) sD = Dvec[c];
    __syncthreads();

    const int    l0   = t * 16;
    const size_t base = ((size_t)b * DMODEL + c) * LSEQ;

    float uv[16];
    {
        const float4* up = reinterpret_cast<const float4*>(u + base + l0);
        #pragma unroll
        for (int i = 0; i < 4; i++) {
            float4 v = up[i];
            uv[4*i+0]=v.x; uv[4*i+1]=v.y; uv[4*i+2]=v.z; uv[4*i+3]=v.w;
        }
    }

    // ---- pass 1: descending Horner for local T, then -> global frame
    float e1r[NSTATE], e1i[NSTATE], Tr[NSTATE], Ti[NSTATE];
    const float fl0 = (float)l0;
    #pragma unroll
    for (int n = 0; n < NSTATE; n++) {
        float dre = sc[0][n], dim = sc[1][n];
        float er = expf(dre * fl0);
        float sn, cs; sincosf(dim * fl0, &sn, &cs);
        float e0r = er * cs, e0i = er * sn;          // exp(dtA * l0)
        e1r[n] = e0r; e1i[n] = e0i;
        float Abr = sc[2][n], Abi = sc[3][n];
        float tr = 0.0f, ti = 0.0f;
        #pragma unroll
        for (int j = 15; j >= 0; j--) {              // T = Abar*T + u[j]
            float t0 = tr;
            tr = fmaf(Abr, t0, fmaf(-Abi, ti, uv[j]));
            ti = fmaf(Abr, ti, Abi * t0);
        }
        Tr[n] = e0r*tr - e0i*ti;                     // global frame
        Ti[n] = e0r*ti + e0i*tr;
    }

    // ---- block exclusive scan over thread totals (8 independent states)
    float offr[NSTATE], offi[NSTATE];
    #pragma unroll
    for (int n = 0; n < NSTATE; n++) {
        float vr = Tr[n], vi = Ti[n];
        #pragma unroll
        for (int d = 1; d < 64; d <<= 1) {
            float xr = __shfl_up(vr, d);
            float xi = __shfl_up(vi, d);
            if (lane >= d) { vr += xr; vi += xi; }
        }
        if (lane == 63) { swr[n][wave] = vr; swi[n][wave] = vi; }
        offr[n] = vr - Tr[n]; offi[n] = vi - Ti[n];
    }
    __syncthreads();
    #pragma unroll
    for (int n = 0; n < NSTATE; n++) {
        #pragma unroll
        for (int w = 0; w < 4; w++) {
            if (w < wave) { offr[n] += swr[n][w]; offi[n] += swi[n][w]; }
        }
    }

    // ---- pass 2: V recurrence, y_j += Re(P0 * V_j)
    float yv[16];
    #pragma unroll
    for (int j = 0; j < 16; j++) yv[j] = 0.0f;
    const float flp = (float)(LSEQ - 1 - l0);
    #pragma unroll
    for (int n = 0; n < NSTATE; n++) {
        float dre = sc[0][n], dim = sc[1][n];
        float er = expf(dre * flp);
        float sn, cs; sincosf(dim * flp, &sn, &cs);
        float p0r = er * cs, p0i = er * sn;          // exp(dtA*(L-1-l0))
        float wr = sc[6][n], wi = sc[7][n];
        float Pr = wr*p0r - wi*p0i;                  // P0 = w * exp(dtA*(L-1-l0))
        float Pi = wr*p0i + wi*p0r;
        float Abr = sc[2][n], Abi = sc[3][n];
        float Air = sc[4][n], Aii = sc[5][n];
        float E0r = e1r[n], E0i = e1i[n];
        float sr = offr[n], si = offi[n];
        float Vr = Abr*sr - Abi*si;                  // V_{-1} = Abar * S_prev
        float Vi = Abr*si + Abi*sr;
        #pragma unroll
        for (int j = 0; j < 16; j++) {
            float s = uv[j];
            float t0 = Vr;
            Vr = fmaf(Air, t0, fmaf(-Aii, Vi, E0r * s));
            Vi = fmaf(Air, Vi, fmaf( Aii, t0, E0i * s));
            yv[j] = fmaf(Pr, Vr, fmaf(-Pi, Vi, yv[j]));
        }
    }

    // ---- +u*D, exact GELU, bf16 store
    const float Dc = sD;
    #pragma unroll
    for (int j = 0; j < 16; j++) {
        float x = yv[j] + uv[j] * Dc;
        yv[j] = 0.5f * x * (1.0f + erff(x * 0.70710678118654752f));
    }
    {
        uint32 us[16];
        #pragma unroll
        for (int j = 0; j < 16; j++) us[j] = f32_to_bf16_rne(yv[j]);
        uint4 p0, p1;
        p0.x = us[0]  | (us[1]  << 16); p0.y = us[2]  | (us[3]  << 16);
        p0.z = us[4]  | (us[5]  << 16); p0.w = us[6]  | (us[7]  << 16);
        p1.x = us[8]  | (us[9]  << 16); p1.y = us[10] | (us[11] << 16);
        p1.z = us[12] | (us[13] << 16); p1.w = us[14] | (us[15] << 16);
        uint4* yp = reinterpret_cast<uint4*>(y_act + base + l0);
        yp[0] = p0; yp[1] = p1;
    }
}

// ---------------------------------------------------------------------------
// Optional: W fp32 -> (W_hi, W_lo) bf16 split, cached in ws (if it fits).
// ---------------------------------------------------------------------------
__global__ __launch_bounds__(256) void wconv_kernel(const float* __restrict__ W,
                                                    u16* __restrict__ Whi,
                                                    u16* __restrict__ Wlo)
{
    int i = blockIdx.x * 256 + threadIdx.x;
    float4 v = reinterpret_cast<const float4*>(W)[i];
    float f[4] = {v.x, v.y, v.z, v.w};
    uint32 h[4], l[4];
    #pragma unroll
    for (int j = 0; j < 4; j++) {
        h[j] = __float_as_uint(f[j]) >> 16;
        float fhi = __uint_as_float(h[j] << 16);
        l[j] = f32_to_bf16_rne(f[j] - fhi);
    }
    uint2 hp, lp;
    hp.x = h[0] | (h[1] << 16); hp.y = h[2] | (h[3] << 16);
    lp.x = l[0] | (l[1] << 16); lp.y = l[2] | (l[3] << 16);
    reinterpret_cast<uint2*>(Whi)[i] = hp;
    reinterpret_cast<uint2*>(Wlo)[i] = lp;
}

// ---------------------------------------------------------------------------
// Kernel 2: MFMA bf16 GEMM + GLU + weighted reduce (unchanged from round 5).
// ---------------------------------------------------------------------------
#define GBM 256
#define GBN 64
#define GBK 32

template<int WCACHED>
__global__ __launch_bounds__(256, 2) void gemm_mfma_kernel(
    const u16* __restrict__ y,        // [B][512][4096] bf16
    const float* __restrict__ W,      // [1024][512] fp32
    const u16* __restrict__ Whi,
    const u16* __restrict__ Wlo,
    const float* __restrict__ b_out,
    const float* __restrict__ W_dec,
    float* __restrict__ acc)
{
    const int mt = blockIdx.x;   // 0..15 (l tiles)
    const int nt = blockIdx.y;   // 0..7  (o-pair tiles)
    const int b  = blockIdx.z;   // 0..15
    const int t  = threadIdx.x;
    const int wv = t >> 6, ln = t & 63;
    const int l0 = mt * GBM, n0 = nt * GBN;

    __shared__ u16 lds[40960];
    u16* Yt = lds;             // cur*10240 + l*40 + k
    u16* Wt = lds + 20480;     // cur*10240 + hl*5120 + r*40 + k

    const int sy_k2 = (t & 15) * 2;
    const int sy_lc = t >> 4;
    const int sw_r  = t & 127;
    const int sw_kh = t >> 7;
    const int sw_o  = (sw_r < 64) ? (n0 + sw_r) : (448 + n0 + sw_r);

    const u16* ybase = y + (size_t)b * DMODEL * LSEQ;

    f32x4 accA[4][4], accG[4][4];
    #pragma unroll
    for (int i = 0; i < 4; i++)
        #pragma unroll
        for (int j = 0; j < 4; j++)
            #pragma unroll
            for (int r = 0; r < 4; r++) { accA[i][j][r] = 0.0f; accG[i][j][r] = 0.0f; }

    uint4 ya0, ya1, yc0, yc1;
    uint4 wh0, wh1, wl0, wl1;
    float4 wf0, wf1, wf2, wf3;

#define STAGE_LOAD(K0) do {                                                               \
    const uint4* _p0 = reinterpret_cast<const uint4*>(                                    \
        ybase + (size_t)((K0) + sy_k2) * LSEQ + l0 + sy_lc*16);                           \
    const uint4* _p1 = reinterpret_cast<const uint4*>(                                    \
        ybase + (size_t)((K0) + sy_k2 + 1) * LSEQ + l0 + sy_lc*16);                       \
    ya0 = _p0[0]; ya1 = _p0[1]; yc0 = _p1[0]; yc1 = _p1[1];                               \
    if (WCACHED) {                                                                        \
        const uint4* _h = reinterpret_cast<const uint4*>(Whi + (size_t)sw_o*DMODEL + (K0) + sw_kh*16); \
        const uint4* _l = reinterpret_cast<const uint4*>(Wlo + (size_t)sw_o*DMODEL + (K0) + sw_kh*16); \
        wh0 = _h[0]; wh1 = _h[1]; wl0 = _l[0]; wl1 = _l[1];                               \
    } else {                                                                              \
        const float4* _f = reinterpret_cast<const float4*>(W + (size_t)sw_o*DMODEL + (K0) + sw_kh*16); \
        wf0 = _f[0]; wf1 = _f[1]; wf2 = _f[2]; wf3 = _f[3];                               \
    }                                                                                     \
} while (0)

#define STAGE_WRITE(BUF) do {                                                             \
    u16* _yt = Yt + (BUF)*10240;                                                          \
    uint32 _aw[8] = {ya0.x, ya0.y, ya0.z, ya0.w, ya1.x, ya1.y, ya1.z, ya1.w};             \
    uint32 _bw[8] = {yc0.x, yc0.y, yc0.z, yc0.w, yc1.x, yc1.y, yc1.z, yc1.w};             \
    _Pragma("unroll")                                                                     \
    for (int _j = 0; _j < 8; _j++) {                                                      \
        uint32 _lo = (_aw[_j] & 0xFFFFu) | (_bw[_j] << 16);                               \
        uint32 _hi = (_aw[_j] >> 16) | (_bw[_j] & 0xFFFF0000u);                           \
        int _le = sy_lc*16 + 2*_j;                                                        \
        *reinterpret_cast<uint32*>(_yt + _le*40 + sy_k2)     = _lo;                       \
        *reinterpret_cast<uint32*>(_yt + (_le+1)*40 + sy_k2) = _hi;                       \
    }                                                                                     \
    u16* _wt = Wt + (BUF)*10240 + sw_r*40 + sw_kh*16;                                     \
    if (WCACHED) {                                                                        \
        *reinterpret_cast<uint4*>(_wt)        = wh0;                                      \
        *reinterpret_cast<uint4*>(_wt + 8)    = wh1;                                      \
        *reinterpret_cast<uint4*>(_wt + 5120)     = wl0;                                  \
        *reinterpret_cast<uint4*>(_wt + 5120 + 8) = wl1;                                  \
    } else {                                                                              \
        float _ff[16] = {wf0.x,wf0.y,wf0.z,wf0.w, wf1.x,wf1.y,wf1.z,wf1.w,                \
                         wf2.x,wf2.y,wf2.z,wf2.w, wf3.x,wf3.y,wf3.z,wf3.w};               \
        uint32 _hh[16], _ll[16];                                                          \
        _Pragma("unroll")                                                                 \
        for (int _j = 0; _j < 16; _j++) {                                                 \
            _hh[_j] = __float_as_uint(_ff[_j]) >> 16;                                     \
            float _fh = __uint_as_float(_hh[_j] << 16);                                   \
            _ll[_j] = f32_to_bf16_rne(_ff[_j] - _fh);                                     \
        }                                                                                 \
        uint4 _ph0, _ph1, _pl0, _pl1;                                                     \
        _ph0.x=_hh[0]|(_hh[1]<<16);  _ph0.y=_hh[2]|(_hh[3]<<16);                          \
        _ph0.z=_hh[4]|(_hh[5]<<16);  _ph0.w=_hh[6]|(_hh[7]<<16);                          \
        _ph1.x=_hh[8]|(_hh[9]<<16);  _ph1.y=_hh[10]|(_hh[11]<<16);                        \
        _ph1.z=_hh[12]|(_hh[13]<<16);_ph1.w=_hh[14]|(_hh[15]<<16);                        \
        _pl0.x=_ll[0]|(_ll[1]<<16);  _pl0.y=_ll[2]|(_ll[3]<<16);                          \
        _pl0.z=_ll[4]|(_ll[5]<<16);  _pl0.w=_ll[6]|(_ll[7]<<16);                          \
        _pl1.x=_ll[8]|(_ll[9]<<16);  _pl1.y=_ll[10]|(_ll[11]<<16);                        \
        _pl1.z=_ll[12]|(_ll[13]<<16);_pl1.w=_ll[14]|(_ll[15]<<16);                        \
        *reinterpret_cast<uint4*>(_wt)            = _ph0;                                 \
        *reinterpret_cast<uint4*>(_wt + 8)        = _ph1;                                 \
        *reinterpret_cast<uint4*>(_wt + 5120)     = _pl0;                                 \
        *reinterpret_cast<uint4*>(_wt + 5120 + 8) = _pl1;                                 \
    }                                                                                     \
} while (0)

    const int fr = ln & 15;
    const int fq = ln >> 4;

    STAGE_LOAD(0);
    STAGE_WRITE(0);
    __syncthreads();

    for (int kt = 0; kt < DMODEL / GBK; kt++) {
        const int cur = kt & 1;
        if (kt < DMODEL / GBK - 1) STAGE_LOAD((kt + 1) * GBK);

        short8v Af[4];
        #pragma unroll
        for (int mf = 0; mf < 4; mf++)
            Af[mf] = *reinterpret_cast<const short8v*>(
                Yt + cur*10240 + (wv*64 + mf*16 + fr)*40 + fq*8);

        #pragma unroll
        for (int nf = 0; nf < 4; nf++) {
            const u16* wb = Wt + cur*10240 + (nf*16 + fr)*40 + fq*8;
            short8v Bah = *reinterpret_cast<const short8v*>(wb);
            short8v Bal = *reinterpret_cast<const short8v*>(wb + 5120);
            short8v Bgh = *reinterpret_cast<const short8v*>(wb + 64*40);
            short8v Bgl = *reinterpret_cast<const short8v*>(wb + 5120 + 64*40);
            #pragma unroll
            for (int mf = 0; mf < 4; mf++) {
                accA[mf][nf] = __builtin_amdgcn_mfma_f32_16x16x32_bf16(Af[mf], Bah, accA[mf][nf], 0, 0, 0);
                accA[mf][nf] = __builtin_amdgcn_mfma_f32_16x16x32_bf16(Af[mf], Bal, accA[mf][nf], 0, 0, 0);
                accG[mf][nf] = __builtin_amdgcn_mfma_f32_16x16x32_bf16(Af[mf], Bgh, accG[mf][nf], 0, 0, 0);
                accG[mf][nf] = __builtin_amdgcn_mfma_f32_16x16x32_bf16(Af[mf], Bgl, accG[mf][nf], 0, 0, 0);
            }
        }

        if (kt < DMODEL / GBK - 1) STAGE_WRITE(cur ^ 1);
        __syncthreads();
    }

    float part = 0.0f;
    #pragma unroll
    for (int nf = 0; nf < 4; nf++) {
        int o = n0 + nf*16 + fr;
        float ba = b_out[o], bg = b_out[512 + o], wd = W_dec[o];
        #pragma unroll
        for (int mf = 0; mf < 4; mf++)
            #pragma unroll
            for (int r = 0; r < 4; r++) {
                float a = accA[mf][nf][r] + ba;
                float g = accG[mf][nf][r] + bg;
                part = fmaf(wd * a, 1.0f / (1.0f + expf(-g)), part);
            }
    }
    #pragma unroll
    for (int d = 32; d > 0; d >>= 1) part += __shfl_down(part, d);
    float* red = reinterpret_cast<float*>(lds);
    if (ln == 0) red[wv] = part;
    __syncthreads();
    if (t == 0) atomicAdd(&acc[b], red[0] + red[1] + red[2] + red[3]);

#undef STAGE_LOAD
#undef STAGE_WRITE
}

__global__ void finalize_kernel(const float* __restrict__ acc,
                                const float* __restrict__ b_dec,
                                float* __restrict__ out)
{
    int i = threadIdx.x;
    if (i < NBATCH) out[i] = acc[i] * (1.0f / (float)LSEQ) + b_dec[0];
}

// ---------------------------------------------------------------------------
extern "C" void kernel_launch(void* const* d_in, const int* in_sizes, int n_in,
                              void* d_out, int out_size, void* d_ws, size_t ws_size,
                              hipStream_t stream)
{
    const float* u          = (const float*)d_in[0];
    const float* log_dt     = (const float*)d_in[1];
    const float* log_A_real = (const float*)d_in[2];
    const float* A_imag     = (const float*)d_in[3];
    const float* B_re       = (const float*)d_in[4];
    const float* B_im       = (const float*)d_in[5];
    const float* C_re       = (const float*)d_in[6];
    const float* C_im       = (const float*)d_in[7];
    const float* Dvec       = (const float*)d_in[8];
    const float* W_out      = (const float*)d_in[9];
    const float* b_out      = (const float*)d_in[10];
    const float* W_dec      = (const float*)d_in[11];
    const float* b_dec      = (const float*)d_in[12];

    const size_t ybytes = (size_t)NBATCH * DMODEL * LSEQ * sizeof(u16);  // 67,108,864
    float* acc   = (float*)d_ws;
    u16*   y_act = (u16*)((char*)d_ws + 256);
    u16*   Whi   = (u16*)((char*)d_ws + 256 + ybytes);
    u16*   Wlo   = Whi + 1024 * DMODEL;
    const size_t need_cache = 256 + ybytes + (size_t)2 * 1024 * DMODEL * sizeof(u16);
    const bool wcached = (ws_size >= need_cache);

    hipMemsetAsync(acc, 0, 64 * sizeof(float), stream);

    s4d_scan_kernel<<<dim3(DMODEL, NBATCH), 256, 0, stream>>>(
        u, log_dt, log_A_real, A_imag, B_re, B_im, C_re, C_im, Dvec, y_act);

    if (wcached) {
        wconv_kernel<<<512, 256, 0, stream>>>(W_out, Whi, Wlo);
        gemm_mfma_kernel<1><<<dim3(16, 8, 16), 256, 0, stream>>>(
            y_act, W_out, Whi, Wlo, b_out, W_dec, acc);
    } else {
        gemm_mfma_kernel<0><<<dim3(16, 8, 16), 256, 0, stream>>>(
            y_act, W_out, Whi, Wlo, b_out, W_dec, acc);
    }

    finalize_kernel<<<1, 64, 0, stream>>>(acc, b_dec, (float*)d_out);
}

// Round 10
// 479.851 us; speedup vs baseline: 2.3759x; 1.0518x over previous
//
#include <hip/hip_runtime.h>
#include <math.h>

#define LSEQ   4096
#define DMODEL 512
#define NSTATE 8
#define NBATCH 16

typedef unsigned int   uint32;
typedef unsigned short u16;

typedef __attribute__((ext_vector_type(8))) short short8v;  // 8 bf16 = 4 VGPR
typedef __attribute__((ext_vector_type(4))) float f32x4;    // MFMA acc

__device__ __forceinline__ uint32 f32_to_bf16_rne(float f) {
    uint32 x = __float_as_uint(f);
    return (x + 0x7FFFu + ((x >> 16) & 1u)) >> 16;
}

// branch-free tanh-form GELU via native exp (err <= ~1e-3 abs, cancels in
// the random-sign contraction downstream; y is bf16-quantized anyway)
__device__ __forceinline__ float gelu_tanh(float x) {
    float x2 = x * x;
    float inner = x * fmaf(0.035677408136f, x2, 0.7978845608028654f);
    float e = __expf(2.0f * inner);          // v_exp
    float th = 1.0f - 2.0f / (e + 1.0f);     // tanh(inner)
    return 0.5f * x * (1.0f + th);
}

// ---------------------------------------------------------------------------
// Kernel 1: S4D scan. Descending-Horner pass 1, V-recurrence pass 2; all
// per-thread transcendentals native (__expf/__sinf/__cosf); GELU branch-free.
// ---------------------------------------------------------------------------
__global__ __launch_bounds__(256) void s4d_scan_kernel(
    const float* __restrict__ u,
    const float* __restrict__ log_dt,
    const float* __restrict__ log_A_real,
    const float* __restrict__ A_imag,
    const float* __restrict__ B_re, const float* __restrict__ B_im,
    const float* __restrict__ C_re, const float* __restrict__ C_im,
    const float* __restrict__ Dvec,
    u16* __restrict__ y_act)
{
    const int c    = blockIdx.x;
    const int b    = blockIdx.y;
    const int t    = threadIdx.x;
    const int lane = t & 63;
    const int wave = t >> 6;

    // per-state constants: 0 dtA_re, 1 dtA_im, 2 Abar_re, 3 Abar_im,
    //                      4 AbarInv_re, 5 AbarInv_im, 6 w_re, 7 w_im
    __shared__ float sc[8][NSTATE];
    __shared__ float sD;
    __shared__ float swr[NSTATE][4], swi[NSTATE][4];

    if (t < NSTATE) {
        const int n = t;
        float dt  = expf(log_dt[c]);
        float Are = -expf(log_A_real[c*NSTATE + n]);
        float Aim = A_imag[c*NSTATE + n];
        float dre = Are * dt, dim = Aim * dt;
        float er  = expf(dre);
        float sn, cs; sincosf(dim, &sn, &cs);
        float Abr = er * cs, Abi = er * sn;
        float eri = expf(-dre);
        float Air = eri * cs, Aii = -eri * sn;
        float nr = Abr - 1.0f, ni = Abi;
        float den = Are*Are + Aim*Aim;
        float qr = (nr*Are + ni*Aim) / den;
        float qi = (ni*Are - nr*Aim) / den;
        float Br = B_re[c*NSTATE + n], Bi = B_im[c*NSTATE + n];
        float Bbr = qr*Br - qi*Bi, Bbi = qr*Bi + qi*Br;
        float Cr = C_re[c*NSTATE + n], Ci = C_im[c*NSTATE + n];
        float wr = Cr*Bbr - Ci*Bbi, wi = Cr*Bbi + Ci*Bbr;
        sc[0][n]=dre; sc[1][n]=dim; sc[2][n]=Abr; sc[3][n]=Abi;
        sc[4][n]=Air; sc[5][n]=Aii; sc[6][n]=wr;  sc[7][n]=wi;
    }
    if (t == 0) sD = Dvec[c];
    __syncthreads();

    const int    l0   = t * 16;
    const size_t base = ((size_t)b * DMODEL + c) * LSEQ;

    float uv[16];
    {
        const float4* up = reinterpret_cast<const float4*>(u + base + l0);
        #pragma unroll
        for (int i = 0; i < 4; i++) {
            float4 v = up[i];
            uv[4*i+0]=v.x; uv[4*i+1]=v.y; uv[4*i+2]=v.z; uv[4*i+3]=v.w;
        }
    }

    // ---- pass 1: descending Horner for local T, then -> global frame
    float e1r[NSTATE], e1i[NSTATE], Tr[NSTATE], Ti[NSTATE];
    const float fl0 = (float)l0;
    #pragma unroll
    for (int n = 0; n < NSTATE; n++) {
        float dre = sc[0][n], dim = sc[1][n];
        float er = __expf(dre * fl0);                // native
        float ph = dim * fl0;
        float sn = __sinf(ph), cs = __cosf(ph);      // native
        float e0r = er * cs, e0i = er * sn;          // exp(dtA * l0)
        e1r[n] = e0r; e1i[n] = e0i;
        float Abr = sc[2][n], Abi = sc[3][n];
        float tr = 0.0f, ti = 0.0f;
        #pragma unroll
        for (int j = 15; j >= 0; j--) {              // T = Abar*T + u[j]
            float t0 = tr;
            tr = fmaf(Abr, t0, fmaf(-Abi, ti, uv[j]));
            ti = fmaf(Abr, ti, Abi * t0);
        }
        Tr[n] = e0r*tr - e0i*ti;                     // global frame
        Ti[n] = e0r*ti + e0i*tr;
    }

    // ---- block exclusive scan over thread totals (8 independent states)
    float offr[NSTATE], offi[NSTATE];
    #pragma unroll
    for (int n = 0; n < NSTATE; n++) {
        float vr = Tr[n], vi = Ti[n];
        #pragma unroll
        for (int d = 1; d < 64; d <<= 1) {
            float xr = __shfl_up(vr, d);
            float xi = __shfl_up(vi, d);
            if (lane >= d) { vr += xr; vi += xi; }
        }
        if (lane == 63) { swr[n][wave] = vr; swi[n][wave] = vi; }
        offr[n] = vr - Tr[n]; offi[n] = vi - Ti[n];
    }
    __syncthreads();
    #pragma unroll
    for (int n = 0; n < NSTATE; n++) {
        #pragma unroll
        for (int w = 0; w < 4; w++) {
            if (w < wave) { offr[n] += swr[n][w]; offi[n] += swi[n][w]; }
        }
    }

    // ---- pass 2: V recurrence, y_j += Re(P0 * V_j)
    float yv[16];
    #pragma unroll
    for (int j = 0; j < 16; j++) yv[j] = 0.0f;
    const float flp = (float)(LSEQ - 1 - l0);
    #pragma unroll
    for (int n = 0; n < NSTATE; n++) {
        float dre = sc[0][n], dim = sc[1][n];
        float er = __expf(dre * flp);                // native
        float ph = dim * flp;
        float sn = __sinf(ph), cs = __cosf(ph);      // native
        float p0r = er * cs, p0i = er * sn;          // exp(dtA*(L-1-l0))
        float wr = sc[6][n], wi = sc[7][n];
        float Pr = wr*p0r - wi*p0i;                  // P0 = w * exp(dtA*(L-1-l0))
        float Pi = wr*p0i + wi*p0r;
        float Abr = sc[2][n], Abi = sc[3][n];
        float Air = sc[4][n], Aii = sc[5][n];
        float E0r = e1r[n], E0i = e1i[n];
        float sr = offr[n], si = offi[n];
        float Vr = Abr*sr - Abi*si;                  // V_{-1} = Abar * S_prev
        float Vi = Abr*si + Abi*sr;
        #pragma unroll
        for (int j = 0; j < 16; j++) {
            float s = uv[j];
            float t0 = Vr;
            Vr = fmaf(Air, t0, fmaf(-Aii, Vi, E0r * s));
            Vi = fmaf(Air, Vi, fmaf( Aii, t0, E0i * s));
            yv[j] = fmaf(Pr, Vr, fmaf(-Pi, Vi, yv[j]));
        }
    }

    // ---- +u*D, branch-free GELU, bf16 store
    const float Dc = sD;
    #pragma unroll
    for (int j = 0; j < 16; j++) {
        float x = fmaf(uv[j], Dc, yv[j]);
        yv[j] = gelu_tanh(x);
    }
    {
        uint32 us[16];
        #pragma unroll
        for (int j = 0; j < 16; j++) us[j] = f32_to_bf16_rne(yv[j]);
        uint4 p0, p1;
        p0.x = us[0]  | (us[1]  << 16); p0.y = us[2]  | (us[3]  << 16);
        p0.z = us[4]  | (us[5]  << 16); p0.w = us[6]  | (us[7]  << 16);
        p1.x = us[8]  | (us[9]  << 16); p1.y = us[10] | (us[11] << 16);
        p1.z = us[12] | (us[13] << 16); p1.w = us[14] | (us[15] << 16);
        uint4* yp = reinterpret_cast<uint4*>(y_act + base + l0);
        yp[0] = p0; yp[1] = p1;
    }
}

// ---------------------------------------------------------------------------
// Optional: W fp32 -> (W_hi, W_lo) bf16 split, cached in ws (if it fits).
// ---------------------------------------------------------------------------
__global__ __launch_bounds__(256) void wconv_kernel(const float* __restrict__ W,
                                                    u16* __restrict__ Whi,
                                                    u16* __restrict__ Wlo)
{
    int i = blockIdx.x * 256 + threadIdx.x;
    float4 v = reinterpret_cast<const float4*>(W)[i];
    float f[4] = {v.x, v.y, v.z, v.w};
    uint32 h[4], l[4];
    #pragma unroll
    for (int j = 0; j < 4; j++) {
        h[j] = __float_as_uint(f[j]) >> 16;
        float fhi = __uint_as_float(h[j] << 16);
        l[j] = f32_to_bf16_rne(f[j] - fhi);
    }
    uint2 hp, lp;
    hp.x = h[0] | (h[1] << 16); hp.y = h[2] | (h[3] << 16);
    lp.x = l[0] | (l[1] << 16); lp.y = l[2] | (l[3] << 16);
    reinterpret_cast<uint2*>(Whi)[i] = hp;
    reinterpret_cast<uint2*>(Wlo)[i] = lp;
}

// ---------------------------------------------------------------------------
// Kernel 2: MFMA bf16 GEMM + GLU + weighted reduce.
// ---------------------------------------------------------------------------
#define GBM 256
#define GBN 64
#define GBK 32

template<int WCACHED>
__global__ __launch_bounds__(256, 2) void gemm_mfma_kernel(
    const u16* __restrict__ y,        // [B][512][4096] bf16
    const float* __restrict__ W,      // [1024][512] fp32
    const u16* __restrict__ Whi,
    const u16* __restrict__ Wlo,
    const float* __restrict__ b_out,
    const float* __restrict__ W_dec,
    float* __restrict__ acc)
{
    const int mt = blockIdx.x;   // 0..15 (l tiles)
    const int nt = blockIdx.y;   // 0..7  (o-pair tiles)
    const int b  = blockIdx.z;   // 0..15
    const int t  = threadIdx.x;
    const int wv = t >> 6, ln = t & 63;
    const int l0 = mt * GBM, n0 = nt * GBN;

    __shared__ u16 lds[40960];
    u16* Yt = lds;             // cur*10240 + l*40 + k
    u16* Wt = lds + 20480;     // cur*10240 + hl*5120 + r*40 + k

    const int sy_k2 = (t & 15) * 2;
    const int sy_lc = t >> 4;
    const int sw_r  = t & 127;
    const int sw_kh = t >> 7;
    const int sw_o  = (sw_r < 64) ? (n0 + sw_r) : (448 + n0 + sw_r);

    const u16* ybase = y + (size_t)b * DMODEL * LSEQ;

    f32x4 accA[4][4], accG[4][4];
    #pragma unroll
    for (int i = 0; i < 4; i++)
        #pragma unroll
        for (int j = 0; j < 4; j++)
            #pragma unroll
            for (int r = 0; r < 4; r++) { accA[i][j][r] = 0.0f; accG[i][j][r] = 0.0f; }

    uint4 ya0, ya1, yc0, yc1;
    uint4 wh0, wh1, wl0, wl1;
    float4 wf0, wf1, wf2, wf3;

#define STAGE_LOAD(K0) do {                                                               \
    const uint4* _p0 = reinterpret_cast<const uint4*>(                                    \
        ybase + (size_t)((K0) + sy_k2) * LSEQ + l0 + sy_lc*16);                           \
    const uint4* _p1 = reinterpret_cast<const uint4*>(                                    \
        ybase + (size_t)((K0) + sy_k2 + 1) * LSEQ + l0 + sy_lc*16);                       \
    ya0 = _p0[0]; ya1 = _p0[1]; yc0 = _p1[0]; yc1 = _p1[1];                               \
    if (WCACHED) {                                                                        \
        const uint4* _h = reinterpret_cast<const uint4*>(Whi + (size_t)sw_o*DMODEL + (K0) + sw_kh*16); \
        const uint4* _l = reinterpret_cast<const uint4*>(Wlo + (size_t)sw_o*DMODEL + (K0) + sw_kh*16); \
        wh0 = _h[0]; wh1 = _h[1]; wl0 = _l[0]; wl1 = _l[1];                               \
    } else {                                                                              \
        const float4* _f = reinterpret_cast<const float4*>(W + (size_t)sw_o*DMODEL + (K0) + sw_kh*16); \
        wf0 = _f[0]; wf1 = _f[1]; wf2 = _f[2]; wf3 = _f[3];                               \
    }                                                                                     \
} while (0)

#define STAGE_WRITE(BUF) do {                                                             \
    u16* _yt = Yt + (BUF)*10240;                                                          \
    uint32 _aw[8] = {ya0.x, ya0.y, ya0.z, ya0.w, ya1.x, ya1.y, ya1.z, ya1.w};             \
    uint32 _bw[8] = {yc0.x, yc0.y, yc0.z, yc0.w, yc1.x, yc1.y, yc1.z, yc1.w};             \
    _Pragma("unroll")                                                                     \
    for (int _j = 0; _j < 8; _j++) {                                                      \
        uint32 _lo = (_aw[_j] & 0xFFFFu) | (_bw[_j] << 16);                               \
        uint32 _hi = (_aw[_j] >> 16) | (_bw[_j] & 0xFFFF0000u);                           \
        int _le = sy_lc*16 + 2*_j;                                                        \
        *reinterpret_cast<uint32*>(_yt + _le*40 + sy_k2)     = _lo;                       \
        *reinterpret_cast<uint32*>(_yt + (_le+1)*40 + sy_k2) = _hi;                       \
    }                                                                                     \
    u16* _wt = Wt + (BUF)*10240 + sw_r*40 + sw_kh*16;                                     \
    if (WCACHED) {                                                                        \
        *reinterpret_cast<uint4*>(_wt)        = wh0;                                      \
        *reinterpret_cast<uint4*>(_wt + 8)    = wh1;                                      \
        *reinterpret_cast<uint4*>(_wt + 5120)     = wl0;                                  \
        *reinterpret_cast<uint4*>(_wt + 5120 + 8) = wl1;                                  \
    } else {                                                                              \
        float _ff[16] = {wf0.x,wf0.y,wf0.z,wf0.w, wf1.x,wf1.y,wf1.z,wf1.w,                \
                         wf2.x,wf2.y,wf2.z,wf2.w, wf3.x,wf3.y,wf3.z,wf3.w};               \
        uint32 _hh[16], _ll[16];                                                          \
        _Pragma("unroll")                                                                 \
        for (int _j = 0; _j < 16; _j++) {                                                 \
            _hh[_j] = __float_as_uint(_ff[_j]) >> 16;                                     \
            float _fh = __uint_as_float(_hh[_j] << 16);                                   \
            _ll[_j] = f32_to_bf16_rne(_ff[_j] - _fh);                                     \
        }                                                                                 \
        uint4 _ph0, _ph1, _pl0, _pl1;                                                     \
        _ph0.x=_hh[0]|(_hh[1]<<16);  _ph0.y=_hh[2]|(_hh[3]<<16);                          \
        _ph0.z=_hh[4]|(_hh[5]<<16);  _ph0.w=_hh[6]|(_hh[7]<<16);                          \
        _ph1.x=_hh[8]|(_hh[9]<<16);  _ph1.y=_hh[10]|(_hh[11]<<16);                        \
        _ph1.z=_hh[12]|(_hh[13]<<16);_ph1.w=_hh[14]|(_hh[15]<<16);                        \
        _pl0.x=_ll[0]|(_ll[1]<<16);  _pl0.y=_ll[2]|(_ll[3]<<16);                          \
        _pl0.z=_ll[4]|(_ll[5]<<16);  _pl0.w=_ll[6]|(_ll[7]<<16);                          \
        _pl1.x=_ll[8]|(_ll[9]<<16);  _pl1.y=_ll[10]|(_ll[11]<<16);                        \
        _pl1.z=_ll[12]|(_ll[13]<<16);_pl1.w=_ll[14]|(_ll[15]<<16);                        \
        *reinterpret_cast<uint4*>(_wt)            = _ph0;                                 \
        *reinterpret_cast<uint4*>(_wt + 8)        = _ph1;                                 \
        *reinterpret_cast<uint4*>(_wt + 5120)     = _pl0;                                 \
        *reinterpret_cast<uint4*>(_wt + 5120 + 8) = _pl1;                                 \
    }                                                                                     \
} while (0)

    const int fr = ln & 15;
    const int fq = ln >> 4;

    STAGE_LOAD(0);
    STAGE_WRITE(0);
    __syncthreads();

    for (int kt = 0; kt < DMODEL / GBK; kt++) {
        const int cur = kt & 1;
        if (kt < DMODEL / GBK - 1) STAGE_LOAD((kt + 1) * GBK);

        short8v Af[4];
        #pragma unroll
        for (int mf = 0; mf < 4; mf++)
            Af[mf] = *reinterpret_cast<const short8v*>(
                Yt + cur*10240 + (wv*64 + mf*16 + fr)*40 + fq*8);

        #pragma unroll
        for (int nf = 0; nf < 4; nf++) {
            const u16* wb = Wt + cur*10240 + (nf*16 + fr)*40 + fq*8;
            short8v Bah = *reinterpret_cast<const short8v*>(wb);
            short8v Bal = *reinterpret_cast<const short8v*>(wb + 5120);
            short8v Bgh = *reinterpret_cast<const short8v*>(wb + 64*40);
            short8v Bgl = *reinterpret_cast<const short8v*>(wb + 5120 + 64*40);
            #pragma unroll
            for (int mf = 0; mf < 4; mf++) {
                accA[mf][nf] = __builtin_amdgcn_mfma_f32_16x16x32_bf16(Af[mf], Bah, accA[mf][nf], 0, 0, 0);
                accA[mf][nf] = __builtin_amdgcn_mfma_f32_16x16x32_bf16(Af[mf], Bal, accA[mf][nf], 0, 0, 0);
                accG[mf][nf] = __builtin_amdgcn_mfma_f32_16x16x32_bf16(Af[mf], Bgh, accG[mf][nf], 0, 0, 0);
                accG[mf][nf] = __builtin_amdgcn_mfma_f32_16x16x32_bf16(Af[mf], Bgl, accG[mf][nf], 0, 0, 0);
            }
        }

        if (kt < DMODEL / GBK - 1) STAGE_WRITE(cur ^ 1);
        __syncthreads();
    }

    float part = 0.0f;
    #pragma unroll
    for (int nf = 0; nf < 4; nf++) {
        int o = n0 + nf*16 + fr;
        float ba = b_out[o], bg = b_out[512 + o], wd = W_dec[o];
        #pragma unroll
        for (int mf = 0; mf < 4; mf++)
            #pragma unroll
            for (int r = 0; r < 4; r++) {
                float a = accA[mf][nf][r] + ba;
                float g = accG[mf][nf][r] + bg;
                part = fmaf(wd * a, 1.0f / (1.0f + __expf(-g)), part);
            }
    }
    #pragma unroll
    for (int d = 32; d > 0; d >>= 1) part += __shfl_down(part, d);
    float* red = reinterpret_cast<float*>(lds);
    if (ln == 0) red[wv] = part;
    __syncthreads();
    if (t == 0) atomicAdd(&acc[b], red[0] + red[1] + red[2] + red[3]);

#undef STAGE_LOAD
#undef STAGE_WRITE
}

__global__ void finalize_kernel(const float* __restrict__ acc,
                                const float* __restrict__ b_dec,
                                float* __restrict__ out)
{
    int i = threadIdx.x;
    if (i < NBATCH) out[i] = acc[i] * (1.0f / (float)LSEQ) + b_dec[0];
}

// ---------------------------------------------------------------------------
extern "C" void kernel_launch(void* const* d_in, const int* in_sizes, int n_in,
                              void* d_out, int out_size, void* d_ws, size_t ws_size,
                              hipStream_t stream)
{
    const float* u          = (const float*)d_in[0];
    const float* log_dt     = (const float*)d_in[1];
    const float* log_A_real = (const float*)d_in[2];
    const float* A_imag     = (const float*)d_in[3];
    const float* B_re       = (const float*)d_in[4];
    const float* B_im       = (const float*)d_in[5];
    const float* C_re       = (const float*)d_in[6];
    const float* C_im       = (const float*)d_in[7];
    const float* Dvec       = (const float*)d_in[8];
    const float* W_out      = (const float*)d_in[9];
    const float* b_out      = (const float*)d_in[10];
    const float* W_dec      = (const float*)d_in[11];
    const float* b_dec      = (const float*)d_in[12];

    const size_t ybytes = (size_t)NBATCH * DMODEL * LSEQ * sizeof(u16);  // 67,108,864
    float* acc   = (float*)d_ws;
    u16*   y_act = (u16*)((char*)d_ws + 256);
    u16*   Whi   = (u16*)((char*)d_ws + 256 + ybytes);
    u16*   Wlo   = Whi + 1024 * DMODEL;
    const size_t need_cache = 256 + ybytes + (size_t)2 * 1024 * DMODEL * sizeof(u16);
    const bool wcached = (ws_size >= need_cache);

    hipMemsetAsync(acc, 0, 64 * sizeof(float), stream);

    s4d_scan_kernel<<<dim3(DMODEL, NBATCH), 256, 0, stream>>>(
        u, log_dt, log_A_real, A_imag, B_re, B_im, C_re, C_im, Dvec, y_act);

    if (wcached) {
        wconv_kernel<<<512, 256, 0, stream>>>(W_out, Whi, Wlo);
        gemm_mfma_kernel<1><<<dim3(16, 8, 16), 256, 0, stream>>>(
            y_act, W_out, Whi, Wlo, b_out, W_dec, acc);
    } else {
        gemm_mfma_kernel<0><<<dim3(16, 8, 16), 256, 0, stream>>>(
            y_act, W_out, Whi, Wlo, b_out, W_dec, acc);
    }

    finalize_kernel<<<1, 64, 0, stream>>>(acc, b_dec, (float*)d_out);
}